// Round 5
// baseline (210.191 us; speedup 1.0000x reference)
//
#include <hip/hip_runtime.h>
#include <cstdint>
#include <cstddef>

// Linear attention: B=4 N=4096 C=768 H=12 d=64
// Pipeline: fused cast->bf16, GEMM1 128x128 m97-style w/ operand-swapped
// packed epilogue (x@Wqkv^T, fused phi), kv/ksum partials, reduce,
// y = z*(q.kv^T), GEMM2 (y@Wproj^T + bias).

typedef __attribute__((ext_vector_type(8))) short bf16x8;
typedef __attribute__((ext_vector_type(4))) float f32x4;

__device__ __forceinline__ unsigned short f2bf(float f) {
  uint32_t u = __builtin_bit_cast(uint32_t, f);
  u += 0x7FFFu + ((u >> 16) & 1u);  // RNE
  return (unsigned short)(u >> 16);
}
__device__ __forceinline__ float bf2f(unsigned short h) {
  uint32_t u = ((uint32_t)h) << 16;
  return __builtin_bit_cast(float, u);
}

// one kernel casting all three fp32 inputs to contiguous bf16 buffers
__global__ __launch_bounds__(256) void cast3_kernel(
    const float* __restrict__ a, const float* __restrict__ b,
    const float* __restrict__ c, unsigned short* __restrict__ oa,
    unsigned short* __restrict__ ob, unsigned short* __restrict__ oc,
    int na4, int nb4, int nc4) {
  int i = blockIdx.x * 256 + threadIdx.x;
  const float* src;
  unsigned short* dst;
  if (i < na4) {
    src = a; dst = oa;
  } else if (i < na4 + nb4) {
    i -= na4; src = b; dst = ob;
  } else if (i < na4 + nb4 + nc4) {
    i -= na4 + nb4; src = c; dst = oc;
  } else {
    return;
  }
  float4 v = reinterpret_cast<const float4*>(src)[i];
  ushort4 o;
  o.x = f2bf(v.x); o.y = f2bf(v.y); o.z = f2bf(v.z); o.w = f2bf(v.w);
  reinterpret_cast<ushort4*>(dst)[i] = o;
}

#define GLOAD_LDS16(g, s)                                                     \
  __builtin_amdgcn_global_load_lds(                                           \
      (const __attribute__((address_space(1))) void*)(g),                     \
      (__attribute__((address_space(3))) void*)(s), 16, 0, 0)

// ============================================================================
// m97-style 128x128 tile, BK=64, 4 waves (2x2 of 64x64), 4x4 16x16x32 frags
// per wave, global_load_lds width-16, plain __syncthreads (2 per K-step),
// XOR chunk swizzle both-sides (rule #21), bijective XCD swizzle (m204).
//
// Epilogue: MFMA operands SWAPPED (mfma(b_frag, a_frag)) -> output tile is
// transposed relative to the standard C/D map, giving
//   row = wm + mi*16 + (lane&15),  col = wn + ni*16 + (lane>>4)*4 + reg
// i.e. each lane holds 4 CONSECUTIVE COLUMNS of one row -> packed
// ushort4 (bf16) / float4 (f32) stores, 16 per thread instead of 64 scalar.
// ============================================================================
template <int PHI_COLS, bool OUT_BF16, bool BIAS>
__global__ __launch_bounds__(256) void gemm128(
    const unsigned short* __restrict__ A, const unsigned short* __restrict__ B,
    void* __restrict__ Cout, const float* __restrict__ bias, int M, int N, int K) {
  __shared__ unsigned short As[128 * 64];
  __shared__ unsigned short Bs[128 * 64];
  const int t = threadIdx.x;
  const int w = t >> 6;
  const int l = t & 63;
  const int r16 = l & 15;
  const int c4 = l >> 4;

  // bijective XCD swizzle over linear block id (m204)
  const int nx = gridDim.x;
  const int nwg = gridDim.x * gridDim.y;
  int lin = blockIdx.y * nx + blockIdx.x;
  {
    const int q = nwg >> 3, r = nwg & 7;
    const int xcd = lin & 7, idx = lin >> 3;
    lin = (xcd < r ? xcd * (q + 1) : r * (q + 1) + (xcd - r) * q) + idx;
  }
  const int m0 = (lin / nx) * 128;
  const int n0 = (lin % nx) * 128;

  // staging: instr i covers rows i*32 + (t>>3), chunk t&7 of that row.
  // LDS linear (lane*16B); global source chunk pre-swizzled by row&7.
  const int srow = t >> 3;                      // 0..31
  const int schunk = (t & 7) ^ ((t >> 3) & 7);  // (chunk) ^ (row&7)
  const unsigned short* gA = A + (size_t)(m0 + srow) * K + schunk * 8;
  const unsigned short* gB = B + (size_t)(n0 + srow) * K + schunk * 8;
  const int lbase = w * 512;  // + i*2048; HW adds lane*8 ushorts

  const int wm = (w >> 1) * 64;
  const int wn = (w & 1) * 64;

  f32x4 acc[4][4] = {};

  for (int k0 = 0; k0 < K; k0 += 64) {
#pragma unroll
    for (int i = 0; i < 4; ++i) {
      GLOAD_LDS16(gA + k0 + (size_t)i * 32 * K, &As[lbase + i * 2048]);
      GLOAD_LDS16(gB + k0 + (size_t)i * 32 * K, &Bs[lbase + i * 2048]);
    }
    __syncthreads();
#pragma unroll
    for (int kk = 0; kk < 2; ++kk) {
      bf16x8 af[4], bfr[4];
#pragma unroll
      for (int mi = 0; mi < 4; ++mi) {
        const int R = wm + mi * 16 + r16;
        const int ch = (kk * 4 + c4) ^ (R & 7);
        af[mi] = *reinterpret_cast<const bf16x8*>(&As[R * 64 + ch * 8]);
      }
#pragma unroll
      for (int ni = 0; ni < 4; ++ni) {
        const int R = wn + ni * 16 + r16;
        const int ch = (kk * 4 + c4) ^ (R & 7);
        bfr[ni] = *reinterpret_cast<const bf16x8*>(&Bs[R * 64 + ch * 8]);
      }
      // operand-swapped: D^T convention (see header comment)
#pragma unroll
      for (int mi = 0; mi < 4; ++mi)
#pragma unroll
        for (int ni = 0; ni < 4; ++ni)
          acc[mi][ni] = __builtin_amdgcn_mfma_f32_16x16x32_bf16(bfr[ni], af[mi], acc[mi][ni], 0, 0, 0);
    }
    __syncthreads();
  }

  // epilogue (swapped map): row = wm+mi*16+r16, col = wn+ni*16+c4*4+reg
  const int orow = m0 + wm + r16;
  const int ocol = n0 + wn + c4 * 4;
#pragma unroll
  for (int ni = 0; ni < 4; ++ni) {
    const int colb = ocol + ni * 16;
    float4 bv = {0.f, 0.f, 0.f, 0.f};
    if constexpr (BIAS) bv = *reinterpret_cast<const float4*>(&bias[colb]);
#pragma unroll
    for (int mi = 0; mi < 4; ++mi) {
      const int row = orow + mi * 16;
      f32x4 v = acc[mi][ni];
      float e[4];
#pragma unroll
      for (int r = 0; r < 4; ++r) {
        float x = v[r];
        if constexpr (BIAS) x += (&bv.x)[r];
        if constexpr (PHI_COLS > 0) {
          if (colb < PHI_COLS) x = (x > 0.0f) ? (x + 1.0f) : __expf(x);  // elu+1
        }
        e[r] = x;
      }
      if constexpr (OUT_BF16) {
        ushort4 o;
        o.x = f2bf(e[0]); o.y = f2bf(e[1]); o.z = f2bf(e[2]); o.w = f2bf(e[3]);
        *reinterpret_cast<ushort4*>(&((unsigned short*)Cout)[(size_t)row * N + colb]) = o;
      } else {
        float4 o = {e[0], e[1], e[2], e[3]};
        *reinterpret_cast<float4*>(&((float*)Cout)[(size_t)row * N + colb]) = o;
      }
    }
  }
}

// kv[m,d] = sum_n k[n,d]*v[n,m]; ksum[d] = sum_n k[n,d].  Partial over 256-n
// chunks, 16 chunks per (b,h).  Thread owns a 4x4 (m,d) tile.
__global__ __launch_bounds__(256) void kv_partial_kernel(
    const unsigned short* __restrict__ qkv, float* __restrict__ kv_part,
    float* __restrict__ ksum_part) {
  const int bh = blockIdx.x;     // 48
  const int chunk = blockIdx.y;  // 16
  const int b = bh / 12, h = bh % 12;
  const int t = threadIdx.x;
  const int tm = (t >> 4) * 4;
  const int td = (t & 15) * 4;
  const unsigned short* base = qkv + ((size_t)(b * 4096 + chunk * 256)) * 2304;
  const unsigned short* kptr = base + 768 + h * 64 + td;
  const unsigned short* vptr = base + 1536 + h * 64 + tm;
  float acc[4][4] = {};
  float ks[4] = {};
#pragma unroll 4
  for (int n = 0; n < 256; ++n) {
    const size_t off = (size_t)n * 2304;
    ushort4 ku = *reinterpret_cast<const ushort4*>(kptr + off);
    ushort4 vu = *reinterpret_cast<const ushort4*>(vptr + off);
    float kf[4] = {bf2f(ku.x), bf2f(ku.y), bf2f(ku.z), bf2f(ku.w)};
    float vf[4] = {bf2f(vu.x), bf2f(vu.y), bf2f(vu.z), bf2f(vu.w)};
#pragma unroll
    for (int i = 0; i < 4; ++i)
#pragma unroll
      for (int j = 0; j < 4; ++j) acc[i][j] += vf[i] * kf[j];
#pragma unroll
    for (int j = 0; j < 4; ++j) ks[j] += kf[j];
  }
  float* kvp = kv_part + ((size_t)(bh * 16 + chunk)) * 4096;
#pragma unroll
  for (int i = 0; i < 4; ++i)
#pragma unroll
    for (int j = 0; j < 4; ++j) kvp[(tm + i) * 64 + td + j] = acc[i][j];
  if (tm == 0) {
    float* ksp = ksum_part + (size_t)(bh * 16 + chunk) * 64;
#pragma unroll
    for (int j = 0; j < 4; ++j) ksp[td + j] = ks[j];
  }
}

__global__ __launch_bounds__(256) void kv_reduce_kernel(
    const float* __restrict__ kv_part, const float* __restrict__ ksum_part,
    float* __restrict__ kv, float* __restrict__ ksum) {
  const int bh = blockIdx.x;
  const int t = threadIdx.x;
  for (int e = t; e < 4096; e += 256) {
    float s = 0.f;
#pragma unroll
    for (int c = 0; c < 16; ++c) s += kv_part[((size_t)(bh * 16 + c)) * 4096 + e];
    kv[(size_t)bh * 4096 + e] = s;
  }
  if (t < 64) {
    float s = 0.f;
#pragma unroll
    for (int c = 0; c < 16; ++c) s += ksum_part[(size_t)(bh * 16 + c) * 64 + t];
    ksum[bh * 64 + t] = s;
  }
}

// y[n,m] = z[n] * sum_d q[n,d] kv[m,d];  z[n] = 1/(q[n,:].ksum + eps)
__global__ __launch_bounds__(256) void y_kernel(
    const unsigned short* __restrict__ qkv, const float* __restrict__ kv,
    const float* __restrict__ ksum, unsigned short* __restrict__ ybf) {
  const int bh = blockIdx.x;  // 48
  const int nc = blockIdx.y;  // 64
  const int b = bh / 12, h = bh % 12;
  const int t = threadIdx.x;
  __shared__ float qs[64][64];   // [d][n]
  __shared__ float kvs[64][64];  // [d][m]
  __shared__ float zs[64];
  const int n0 = nc * 64;
  const unsigned short* qbase = qkv + ((size_t)(b * 4096 + n0)) * 2304 + h * 64;
  {
    const int nl = t & 63, dc = t >> 6;
    const unsigned short* qrow = qbase + (size_t)nl * 2304;
    const float* kvrow = kv + (size_t)bh * 4096 + (size_t)nl * 64;
#pragma unroll
    for (int dd = 0; dd < 4; ++dd) {
      const int d0 = dc * 16 + dd * 4;
      ushort4 qu = *reinterpret_cast<const ushort4*>(qrow + d0);
      qs[d0 + 0][nl] = bf2f(qu.x);
      qs[d0 + 1][nl] = bf2f(qu.y);
      qs[d0 + 2][nl] = bf2f(qu.z);
      qs[d0 + 3][nl] = bf2f(qu.w);
      float4 kf = *reinterpret_cast<const float4*>(kvrow + d0);
      kvs[d0 + 0][nl] = kf.x;
      kvs[d0 + 1][nl] = kf.y;
      kvs[d0 + 2][nl] = kf.z;
      kvs[d0 + 3][nl] = kf.w;
    }
  }
  __syncthreads();
  if (t < 64) {
    const float* ksp = ksum + bh * 64;
    float s = 0.f;
#pragma unroll
    for (int d = 0; d < 64; ++d) s += qs[d][t] * ksp[d];
    zs[t] = 1.0f / (s + 1e-6f);
  }
  __syncthreads();
  const int tn = (t >> 4) * 4;
  const int tmm = (t & 15) * 4;
  float acc[4][4] = {};
#pragma unroll 4
  for (int d = 0; d < 64; ++d) {
    float4 qv = *reinterpret_cast<const float4*>(&qs[d][tn]);
    float4 kf = *reinterpret_cast<const float4*>(&kvs[d][tmm]);
    const float qa[4] = {qv.x, qv.y, qv.z, qv.w};
    const float ka[4] = {kf.x, kf.y, kf.z, kf.w};
#pragma unroll
    for (int i = 0; i < 4; ++i)
#pragma unroll
      for (int j = 0; j < 4; ++j) acc[i][j] += qa[i] * ka[j];
  }
  unsigned short* yrow = ybf + ((size_t)(b * 4096 + n0)) * 768 + h * 64;
#pragma unroll
  for (int i = 0; i < 4; ++i) {
    const int n = tn + i;
    const float z = zs[n];
    ushort4 o;
    o.x = f2bf(acc[i][0] * z);
    o.y = f2bf(acc[i][1] * z);
    o.z = f2bf(acc[i][2] * z);
    o.w = f2bf(acc[i][3] * z);
    *reinterpret_cast<ushort4*>(yrow + (size_t)n * 768 + tmm) = o;
  }
}

extern "C" void kernel_launch(void* const* d_in, const int* in_sizes, int n_in,
                              void* d_out, int out_size, void* d_ws, size_t ws_size,
                              hipStream_t stream) {
  const float* x = (const float*)d_in[0];
  const float* Wqkv = (const float*)d_in[1];
  const float* Wproj = (const float*)d_in[2];
  const float* bproj = (const float*)d_in[3];
  float* out = (float*)d_out;

  const int M = 16384;   // B*N tokens
  const int C = 768;
  const int N1 = 2304;   // 3C

  char* ws = (char*)d_ws;
  size_t off = 0;
  unsigned short* xb = (unsigned short*)(ws + off);  off += (size_t)M * C * 2;    // 25.2MB
  unsigned short* wqb = (unsigned short*)(ws + off); off += (size_t)N1 * C * 2;
  unsigned short* wpb = (unsigned short*)(ws + off); off += (size_t)C * C * 2;
  unsigned short* qkvb = (unsigned short*)(ws + off); off += (size_t)M * N1 * 2;
  float* kv = (float*)(ws + off);        off += (size_t)48 * 4096 * 4;
  float* ksum = (float*)(ws + off);      off += (size_t)48 * 64 * 4;
  unsigned short* yb = (unsigned short*)(ws + off); off += (size_t)M * C * 2;
  // kv_part/ksum_part overlay xb (dead after GEMM1): 12.6MB + 0.2MB < 25.2MB
  float* kv_part = (float*)xb;
  float* ksum_part = (float*)(xb + (size_t)48 * 16 * 4096 * 2);  // floats: 12.6MB in

  const int na4 = M * C / 4, nb4 = N1 * C / 4, nc4 = C * C / 4;
  cast3_kernel<<<(na4 + nb4 + nc4 + 255) / 256, 256, 0, stream>>>(
      x, Wqkv, Wproj, xb, wqb, wpb, na4, nb4, nc4);

  // qkv = x @ Wqkv^T, phi fused on q,k columns (col < 1536), bf16 out
  gemm128<1536, true, false>
      <<<dim3(N1 / 128, M / 128), 256, 0, stream>>>(xb, wqb, qkvb, nullptr, M, N1, C);

  kv_partial_kernel<<<dim3(48, 16), 256, 0, stream>>>(qkvb, kv_part, ksum_part);
  kv_reduce_kernel<<<48, 256, 0, stream>>>(kv_part, ksum_part, kv, ksum);
  y_kernel<<<dim3(48, 64), 256, 0, stream>>>(qkvb, kv, ksum, yb);

  // out = y @ Wproj^T + b, fp32 out
  gemm128<0, false, true>
      <<<dim3(C / 128, M / 128), 256, 0, stream>>>(yb, wpb, out, bproj, M, C, C);
}

// Round 6
// 180.945 us; speedup vs baseline: 1.1616x; 1.1616x over previous
//
#include <hip/hip_runtime.h>
#include <cstdint>
#include <cstddef>

// Linear attention: B=4 N=4096 C=768 H=12 d=64
// Pipeline: fused cast->bf16, GEMM1 128x128 m97-style (x@Wqkv^T, fused phi),
// kv/ksum partials, reduce (kv->bf16), y via MFMA (q.kv^T * z), GEMM2.

typedef __attribute__((ext_vector_type(8))) short bf16x8;
typedef __attribute__((ext_vector_type(4))) float f32x4;

__device__ __forceinline__ unsigned short f2bf(float f) {
  uint32_t u = __builtin_bit_cast(uint32_t, f);
  u += 0x7FFFu + ((u >> 16) & 1u);  // RNE
  return (unsigned short)(u >> 16);
}
__device__ __forceinline__ float bf2f(unsigned short h) {
  uint32_t u = ((uint32_t)h) << 16;
  return __builtin_bit_cast(float, u);
}

// one kernel casting all three fp32 inputs to contiguous bf16 buffers
__global__ __launch_bounds__(256) void cast3_kernel(
    const float* __restrict__ a, const float* __restrict__ b,
    const float* __restrict__ c, unsigned short* __restrict__ oa,
    unsigned short* __restrict__ ob, unsigned short* __restrict__ oc,
    int na4, int nb4, int nc4) {
  int i = blockIdx.x * 256 + threadIdx.x;
  const float* src;
  unsigned short* dst;
  if (i < na4) {
    src = a; dst = oa;
  } else if (i < na4 + nb4) {
    i -= na4; src = b; dst = ob;
  } else if (i < na4 + nb4 + nc4) {
    i -= na4 + nb4; src = c; dst = oc;
  } else {
    return;
  }
  float4 v = reinterpret_cast<const float4*>(src)[i];
  ushort4 o;
  o.x = f2bf(v.x); o.y = f2bf(v.y); o.z = f2bf(v.z); o.w = f2bf(v.w);
  reinterpret_cast<ushort4*>(dst)[i] = o;
}

#define GLOAD_LDS16(g, s)                                                     \
  __builtin_amdgcn_global_load_lds(                                           \
      (const __attribute__((address_space(1))) void*)(g),                     \
      (__attribute__((address_space(3))) void*)(s), 16, 0, 0)

// ============================================================================
// m97-style 128x128 tile, BK=64, 4 waves (2x2 of 64x64), 4x4 16x16x32 frags
// per wave, global_load_lds width-16, plain __syncthreads (2 per K-step).
// XOR chunk swizzle both-sides (rule #21), bijective XCD swizzle (m204).
// Epilogue: standard C/D map (col=lane&15 -> consecutive lanes write
// consecutive bf16 -> coalesced 32B segments; round-5's swapped map caused
// 1.5x HBM write amplification).
// ============================================================================
template <int PHI_COLS, bool OUT_BF16, bool BIAS>
__global__ __launch_bounds__(256) void gemm128(
    const unsigned short* __restrict__ A, const unsigned short* __restrict__ B,
    void* __restrict__ Cout, const float* __restrict__ bias, int M, int N, int K) {
  __shared__ unsigned short As[128 * 64];
  __shared__ unsigned short Bs[128 * 64];
  const int t = threadIdx.x;
  const int w = t >> 6;
  const int l = t & 63;
  const int r16 = l & 15;
  const int c4 = l >> 4;

  // bijective XCD swizzle over linear block id (m204)
  const int nx = gridDim.x;
  const int nwg = gridDim.x * gridDim.y;
  int lin = blockIdx.y * nx + blockIdx.x;
  {
    const int q = nwg >> 3, r = nwg & 7;
    const int xcd = lin & 7, idx = lin >> 3;
    lin = (xcd < r ? xcd * (q + 1) : r * (q + 1) + (xcd - r) * q) + idx;
  }
  const int m0 = (lin / nx) * 128;
  const int n0 = (lin % nx) * 128;

  // staging: instr i covers rows i*32 + (t>>3), chunk t&7 of that row.
  // LDS linear (lane*16B); global source chunk pre-swizzled by row&7.
  const int srow = t >> 3;                      // 0..31
  const int schunk = (t & 7) ^ ((t >> 3) & 7);  // (chunk) ^ (row&7)
  const unsigned short* gA = A + (size_t)(m0 + srow) * K + schunk * 8;
  const unsigned short* gB = B + (size_t)(n0 + srow) * K + schunk * 8;
  const int lbase = w * 512;  // + i*2048; HW adds lane*8 ushorts

  const int wm = (w >> 1) * 64;
  const int wn = (w & 1) * 64;

  f32x4 acc[4][4] = {};

  for (int k0 = 0; k0 < K; k0 += 64) {
#pragma unroll
    for (int i = 0; i < 4; ++i) {
      GLOAD_LDS16(gA + k0 + (size_t)i * 32 * K, &As[lbase + i * 2048]);
      GLOAD_LDS16(gB + k0 + (size_t)i * 32 * K, &Bs[lbase + i * 2048]);
    }
    __syncthreads();
#pragma unroll
    for (int kk = 0; kk < 2; ++kk) {
      bf16x8 af[4], bfr[4];
#pragma unroll
      for (int mi = 0; mi < 4; ++mi) {
        const int R = wm + mi * 16 + r16;
        const int ch = (kk * 4 + c4) ^ (R & 7);
        af[mi] = *reinterpret_cast<const bf16x8*>(&As[R * 64 + ch * 8]);
      }
#pragma unroll
      for (int ni = 0; ni < 4; ++ni) {
        const int R = wn + ni * 16 + r16;
        const int ch = (kk * 4 + c4) ^ (R & 7);
        bfr[ni] = *reinterpret_cast<const bf16x8*>(&Bs[R * 64 + ch * 8]);
      }
#pragma unroll
      for (int mi = 0; mi < 4; ++mi)
#pragma unroll
        for (int ni = 0; ni < 4; ++ni)
          acc[mi][ni] = __builtin_amdgcn_mfma_f32_16x16x32_bf16(af[mi], bfr[ni], acc[mi][ni], 0, 0, 0);
    }
    __syncthreads();
  }

  // epilogue: C/D layout col=lane&15, row=(lane>>4)*4+reg (m89/m91 verified)
  const int rbase = c4 * 4;
#pragma unroll
  for (int mi = 0; mi < 4; ++mi) {
    const int row = m0 + wm + mi * 16 + rbase;
#pragma unroll
    for (int ni = 0; ni < 4; ++ni) {
      const int col = n0 + wn + ni * 16 + r16;
      float bv = 0.0f;
      if constexpr (BIAS) bv = bias[col];
      f32x4 v = acc[mi][ni];
#pragma unroll
      for (int r = 0; r < 4; ++r) {
        float x = v[r] + bv;
        if constexpr (PHI_COLS > 0) {
          if (col < PHI_COLS) x = (x > 0.0f) ? (x + 1.0f) : __expf(x);  // elu+1
        }
        if constexpr (OUT_BF16)
          ((unsigned short*)Cout)[(size_t)(row + r) * N + col] = f2bf(x);
        else
          ((float*)Cout)[(size_t)(row + r) * N + col] = x;
      }
    }
  }
}

// kv[m,d] = sum_n k[n,d]*v[n,m]; ksum[d] = sum_n k[n,d].  Partial over 256-n
// chunks, 16 chunks per (b,h).  Thread owns a 4x4 (m,d) tile.
__global__ __launch_bounds__(256) void kv_partial_kernel(
    const unsigned short* __restrict__ qkv, float* __restrict__ kv_part,
    float* __restrict__ ksum_part) {
  const int bh = blockIdx.x;     // 48
  const int chunk = blockIdx.y;  // 16
  const int b = bh / 12, h = bh % 12;
  const int t = threadIdx.x;
  const int tm = (t >> 4) * 4;
  const int td = (t & 15) * 4;
  const unsigned short* base = qkv + ((size_t)(b * 4096 + chunk * 256)) * 2304;
  const unsigned short* kptr = base + 768 + h * 64 + td;
  const unsigned short* vptr = base + 1536 + h * 64 + tm;
  float acc[4][4] = {};
  float ks[4] = {};
#pragma unroll 4
  for (int n = 0; n < 256; ++n) {
    const size_t off = (size_t)n * 2304;
    ushort4 ku = *reinterpret_cast<const ushort4*>(kptr + off);
    ushort4 vu = *reinterpret_cast<const ushort4*>(vptr + off);
    float kf[4] = {bf2f(ku.x), bf2f(ku.y), bf2f(ku.z), bf2f(ku.w)};
    float vf[4] = {bf2f(vu.x), bf2f(vu.y), bf2f(vu.z), bf2f(vu.w)};
#pragma unroll
    for (int i = 0; i < 4; ++i)
#pragma unroll
      for (int j = 0; j < 4; ++j) acc[i][j] += vf[i] * kf[j];
#pragma unroll
    for (int j = 0; j < 4; ++j) ks[j] += kf[j];
  }
  float* kvp = kv_part + ((size_t)(bh * 16 + chunk)) * 4096;
#pragma unroll
  for (int i = 0; i < 4; ++i)
#pragma unroll
    for (int j = 0; j < 4; ++j) kvp[(tm + i) * 64 + td + j] = acc[i][j];
  if (tm == 0) {
    float* ksp = ksum_part + (size_t)(bh * 16 + chunk) * 64;
#pragma unroll
    for (int j = 0; j < 4; ++j) ksp[td + j] = ks[j];
  }
}

// reduce partials; kv emitted as bf16 [m][d] (MFMA B-operand), ksum stays f32
__global__ __launch_bounds__(256) void kv_reduce_kernel(
    const float* __restrict__ kv_part, const float* __restrict__ ksum_part,
    unsigned short* __restrict__ kvb, float* __restrict__ ksum) {
  const int bh = blockIdx.x;
  const int t = threadIdx.x;
  for (int e = t; e < 4096; e += 256) {
    float s = 0.f;
#pragma unroll
    for (int c = 0; c < 16; ++c) s += kv_part[((size_t)(bh * 16 + c)) * 4096 + e];
    kvb[(size_t)bh * 4096 + e] = f2bf(s);
  }
  if (t < 64) {
    float s = 0.f;
#pragma unroll
    for (int c = 0; c < 16; ++c) s += ksum_part[(size_t)(bh * 16 + c) * 64 + t];
    ksum[bh * 64 + t] = s;
  }
}

// ============================================================================
// y[n,m] = z[n] * sum_d q[n,d] kv[m,d], z[n]=1/(q[n,:].ksum+eps), via MFMA.
// Block: one (b,h) x 128 q-rows. Q staged 16KB, kv(bf16) staged 8KB, both
// via global_load_lds with the XOR chunk swizzle (both-sides, rule #21).
// 4 waves x 32 rows, 2x4 16x16x32 frags, K=64 (2 kk). z computed in f32 by
// threads<128 from bf16 q + f32 ksum (same numerics as previous y_kernel).
// ============================================================================
__global__ __launch_bounds__(256) void y_mfma_kernel(
    const unsigned short* __restrict__ qkv, const unsigned short* __restrict__ kvb,
    const float* __restrict__ ksum, unsigned short* __restrict__ ybf) {
  __shared__ unsigned short Qs[128 * 64];  // 16KB
  __shared__ unsigned short KVs[64 * 64];  // 8KB
  __shared__ float zs[128];
  const int bh = blockIdx.x;       // 48
  const int n0 = blockIdx.y * 128; // 32
  const int b = bh / 12, h = bh % 12;
  const int t = threadIdx.x;
  const int w = t >> 6;
  const int l = t & 63;
  const int r16 = l & 15;
  const int c4 = l >> 4;

  const int srow = t >> 3;                      // 0..31
  const int schunk = (t & 7) ^ ((t >> 3) & 7);  // pre-swizzled source chunk
  const unsigned short* gQ =
      qkv + ((size_t)(b * 4096 + n0 + srow)) * 2304 + h * 64 + schunk * 8;
  const unsigned short* gKV = kvb + (size_t)bh * 4096 + srow * 64 + schunk * 8;
  const int lbase = w * 512;
#pragma unroll
  for (int i = 0; i < 4; ++i)
    GLOAD_LDS16(gQ + (size_t)i * 32 * 2304, &Qs[lbase + i * 2048]);
#pragma unroll
  for (int i = 0; i < 2; ++i)
    GLOAD_LDS16(gKV + i * 32 * 64, &KVs[lbase + i * 2048]);
  __syncthreads();

  // MFMA: per wave 32 rows x 64 cols
  const int wr = w * 32;
  f32x4 acc[2][4] = {};
#pragma unroll
  for (int kk = 0; kk < 2; ++kk) {
    bf16x8 af[2], bfr[4];
#pragma unroll
    for (int mi = 0; mi < 2; ++mi) {
      const int R = wr + mi * 16 + r16;
      const int ch = (kk * 4 + c4) ^ (R & 7);
      af[mi] = *reinterpret_cast<const bf16x8*>(&Qs[R * 64 + ch * 8]);
    }
#pragma unroll
    for (int ni = 0; ni < 4; ++ni) {
      const int R = ni * 16 + r16;
      const int ch = (kk * 4 + c4) ^ (R & 7);
      bfr[ni] = *reinterpret_cast<const bf16x8*>(&KVs[R * 64 + ch * 8]);
    }
#pragma unroll
    for (int mi = 0; mi < 2; ++mi)
#pragma unroll
      for (int ni = 0; ni < 4; ++ni)
        acc[mi][ni] = __builtin_amdgcn_mfma_f32_16x16x32_bf16(af[mi], bfr[ni], acc[mi][ni], 0, 0, 0);
  }

  // z for the block's 128 rows (overlaps MFMA drain on waves 0,1)
  if (t < 128) {
    const float* ks = ksum + bh * 64;
    float s = 0.f;
#pragma unroll
    for (int c = 0; c < 8; ++c) {
      bf16x8 qv = *reinterpret_cast<const bf16x8*>(&Qs[t * 64 + ((c ^ (t & 7)) * 8)]);
#pragma unroll
      for (int j = 0; j < 8; ++j) s += bf2f((unsigned short)qv[j]) * ks[c * 8 + j];
    }
    zs[t] = 1.0f / (s + 1e-6f);
  }
  __syncthreads();

  // epilogue: col=lane&15, row=c4*4+reg (standard map)
  unsigned short* ybase = ybf + ((size_t)(b * 4096 + n0)) * 768 + h * 64;
#pragma unroll
  for (int mi = 0; mi < 2; ++mi) {
#pragma unroll
    for (int ni = 0; ni < 4; ++ni) {
      const int col = ni * 16 + r16;
      f32x4 v = acc[mi][ni];
#pragma unroll
      for (int r = 0; r < 4; ++r) {
        const int row = wr + mi * 16 + c4 * 4 + r;
        ybase[(size_t)row * 768 + col] = f2bf(v[r] * zs[row]);
      }
    }
  }
}

extern "C" void kernel_launch(void* const* d_in, const int* in_sizes, int n_in,
                              void* d_out, int out_size, void* d_ws, size_t ws_size,
                              hipStream_t stream) {
  const float* x = (const float*)d_in[0];
  const float* Wqkv = (const float*)d_in[1];
  const float* Wproj = (const float*)d_in[2];
  const float* bproj = (const float*)d_in[3];
  float* out = (float*)d_out;

  const int M = 16384;   // B*N tokens
  const int C = 768;
  const int N1 = 2304;   // 3C

  char* ws = (char*)d_ws;
  size_t off = 0;
  unsigned short* xb = (unsigned short*)(ws + off);  off += (size_t)M * C * 2;    // 25.2MB
  unsigned short* wqb = (unsigned short*)(ws + off); off += (size_t)N1 * C * 2;
  unsigned short* wpb = (unsigned short*)(ws + off); off += (size_t)C * C * 2;
  unsigned short* qkvb = (unsigned short*)(ws + off); off += (size_t)M * N1 * 2;
  unsigned short* kvb = (unsigned short*)(ws + off); off += (size_t)48 * 4096 * 2;
  float* ksum = (float*)(ws + off);      off += (size_t)48 * 64 * 4;
  unsigned short* yb = (unsigned short*)(ws + off); off += (size_t)M * C * 2;
  // kv_part/ksum_part overlay xb (dead after GEMM1): 12.6MB + 0.2MB < 25.2MB
  float* kv_part = (float*)xb;
  float* ksum_part = (float*)(xb + (size_t)48 * 16 * 4096 * 2);  // floats: 12.6MB in

  const int na4 = M * C / 4, nb4 = N1 * C / 4, nc4 = C * C / 4;
  cast3_kernel<<<(na4 + nb4 + nc4 + 255) / 256, 256, 0, stream>>>(
      x, Wqkv, Wproj, xb, wqb, wpb, na4, nb4, nc4);

  // qkv = x @ Wqkv^T, phi fused on q,k columns (col < 1536), bf16 out
  gemm128<1536, true, false>
      <<<dim3(N1 / 128, M / 128), 256, 0, stream>>>(xb, wqb, qkvb, nullptr, M, N1, C);

  kv_partial_kernel<<<dim3(48, 16), 256, 0, stream>>>(qkvb, kv_part, ksum_part);
  kv_reduce_kernel<<<48, 256, 0, stream>>>(kv_part, ksum_part, kvb, ksum);
  y_mfma_kernel<<<dim3(48, 32), 256, 0, stream>>>(qkvb, kvb, ksum, yb);

  // out = y @ Wproj^T + b, fp32 out
  gemm128<0, false, true>
      <<<dim3(C / 128, M / 128), 256, 0, stream>>>(yb, wpb, out, bproj, M, C, C);
}